// Round 1
// baseline (155.845 us; speedup 1.0000x reference)
//
#include <hip/hip_runtime.h>
#include <stdint.h>

#define B_ 2048
#define I_ 16
#define M_ 4
#define R_ 4096
#define C_ 10
#define NX 17           // I+1
#define NW 170          // NX*C

// d_out layout: y_hat (B_*C_) | norm_fs (B_*R_) | x_ext (B_*NX)
#define Y_OFF    0
#define NORM_OFF (B_ * C_)                  // 20480
#define XE_OFF   (B_ * C_ + B_ * R_)        // 8409088

// ---------------- pack rule_idx: 16 x 2-bit indices -> one uint32 per rule ----
__global__ void pack_kernel(const int* __restrict__ rule_idx,
                            uint32_t* __restrict__ packed) {
    int r = blockIdx.x * 256 + threadIdx.x;
    if (r < R_) {
        uint32_t p = 0;
#pragma unroll
        for (int i = 0; i < I_; ++i)
            p |= ((uint32_t)rule_idx[i * R_ + r] & 3u) << (2 * i);
        packed[r] = p;
    }
}

// ---------------- per-batch: mfs pair table, firing, norm_fs, x_ext ----------
__global__ __launch_bounds__(256) void fuzz_kernel(
        const float* __restrict__ x, const float* __restrict__ centers,
        const float* __restrict__ widths, const uint32_t* __restrict__ packed,
        float* __restrict__ out) {
    int b = blockIdx.x;
    int t = threadIdx.x;
    __shared__ float xs[I_];
    __shared__ float tab[8 * 16];   // pair q: tab[q*16 + (hi<<2|lo)] = mf(2q,lo)*mf(2q+1,hi)
    __shared__ float wsum[4];

    if (t < I_) xs[t] = x[b * I_ + t];
    if (t < NX) out[XE_OFF + b * NX + t] = (t < I_) ? x[b * I_ + t] : 1.0f;
    __syncthreads();

    if (t < 128) {
        int q  = t >> 4;
        int hi = (t >> 2) & 3;
        int lo = t & 3;
        int i0 = 2 * q, i1 = 2 * q + 1;
        float d0 = xs[i0] - centers[i0 * M_ + lo];
        float w0 = widths[i0 * M_ + lo];
        float m0 = expf(-(d0 * d0) / (2.0f * w0 * w0) + 1e-9f);
        float d1 = xs[i1] - centers[i1 * M_ + hi];
        float w1 = widths[i1 * M_ + hi];
        float m1 = expf(-(d1 * d1) / (2.0f * w1 * w1) + 1e-9f);
        tab[t] = m0 * m1;
    }
    __syncthreads();

    float fs[16];
    float lsum = 0.f;
#pragma unroll
    for (int k = 0; k < 16; ++k) {
        int r = t + k * 256;
        uint32_t p = packed[r];
        float f = tab[        p        & 15];
        f *= tab[ 16 + ((p >>  4) & 15)];
        f *= tab[ 32 + ((p >>  8) & 15)];
        f *= tab[ 48 + ((p >> 12) & 15)];
        f *= tab[ 64 + ((p >> 16) & 15)];
        f *= tab[ 80 + ((p >> 20) & 15)];
        f *= tab[ 96 + ((p >> 24) & 15)];
        f *= tab[112 + ((p >> 28) & 15)];
        fs[k] = f;
        lsum += f;
    }
#pragma unroll
    for (int off = 32; off > 0; off >>= 1) lsum += __shfl_down(lsum, off);
    if ((t & 63) == 0) wsum[t >> 6] = lsum;
    __syncthreads();
    float inv = 1.0f / (wsum[0] + wsum[1] + wsum[2] + wsum[3] + 1e-9f);
#pragma unroll
    for (int k = 0; k < 16; ++k)
        out[NORM_OFF + (size_t)b * R_ + t + k * 256] = fs[k] * inv;
}

// ---------------- GEMM: part[ks][b][n] = sum_{k in slice} nf[b,k] * W[k,n] ---
#define BM 64
#define KS 32
#define KSPLIT 8
#define KCH (R_ / KSPLIT)   // 512
#define NPAD 192

__global__ __launch_bounds__(256) void gemm_kernel(
        const float* __restrict__ nf,   // (B_, R_) row-major
        const float* __restrict__ W,    // (R_, NW) row-major (consequents)
        float* __restrict__ part) {     // (KSPLIT, B_, NW)
    int bt = blockIdx.x;
    int ks = blockIdx.y;
    int t  = threadIdx.x;
    int bg = t >> 4;    // 0..15 -> 4 consecutive b each
    int ng = t & 15;    // 0..15 -> 12 consecutive n each (padded to 192)
    __shared__ float lw[KS][NPAD];      // 24 KB
    __shared__ float lnf[KS][BM + 4];   // 8.5 KB, k-major for float4 b-reads

    // zero the pad columns once (never rewritten by staging)
    for (int idx = t; idx < KS * NPAD; idx += 256) {
        int n = idx % NPAD;
        if (n >= NW) lw[idx / NPAD][n] = 0.f;
    }

    float acc[4][12];
#pragma unroll
    for (int i = 0; i < 4; ++i)
#pragma unroll
        for (int j = 0; j < 12; ++j) acc[i][j] = 0.f;

    int b0 = bt * BM;
    int k0 = ks * KCH;
    for (int kk = 0; kk < KCH; kk += KS) {
        __syncthreads();
        // stage W tile [KS][170] via float2
        for (int idx = t; idx < KS * 85; idx += 256) {
            int k  = idx / 85;
            int n2 = idx - k * 85;
            float2 v = *(const float2*)(W + (size_t)(k0 + kk + k) * NW + n2 * 2);
            lw[k][n2 * 2]     = v.x;
            lw[k][n2 * 2 + 1] = v.y;
        }
        // stage NF tile transposed -> lnf[k][b]
        {
            int row = t >> 3;   // 0..31
            int c4  = t & 7;    // k-offset group
#pragma unroll
            for (int rr = 0; rr < 2; ++rr) {
                int bb = row + rr * 32;
                float4 v = *(const float4*)(nf + (size_t)(b0 + bb) * R_ + k0 + kk + c4 * 4);
                lnf[c4 * 4 + 0][bb] = v.x;
                lnf[c4 * 4 + 1][bb] = v.y;
                lnf[c4 * 4 + 2][bb] = v.z;
                lnf[c4 * 4 + 3][bb] = v.w;
            }
        }
        __syncthreads();
#pragma unroll 8
        for (int k = 0; k < KS; ++k) {
            float4 a = *(const float4*)(&lnf[k][bg * 4]);
            float av[4] = {a.x, a.y, a.z, a.w};
#pragma unroll
            for (int u = 0; u < 3; ++u) {
                float4 w4 = *(const float4*)(&lw[k][ng * 12 + u * 4]);
                float wv[4] = {w4.x, w4.y, w4.z, w4.w};
#pragma unroll
                for (int bb = 0; bb < 4; ++bb)
#pragma unroll
                    for (int v4 = 0; v4 < 4; ++v4)
                        acc[bb][u * 4 + v4] += av[bb] * wv[v4];
            }
        }
    }
#pragma unroll
    for (int bb = 0; bb < 4; ++bb) {
        int b = b0 + bg * 4 + bb;
#pragma unroll
        for (int u = 0; u < 12; ++u) {
            int n = ng * 12 + u;
            if (n < NW) part[((size_t)ks * B_ + b) * NW + n] = acc[bb][u];
        }
    }
}

// ---------------- reduce K-split partials + contract with x_ext --------------
__global__ __launch_bounds__(192) void finalize_kernel(
        const float* __restrict__ part, const float* __restrict__ x,
        float* __restrict__ out) {
    int b = blockIdx.x;
    int t = threadIdx.x;
    __shared__ float g[NW];
    if (t < NW) {
        float s = 0.f;
#pragma unroll
        for (int ks = 0; ks < KSPLIT; ++ks)
            s += part[((size_t)ks * B_ + b) * NW + t];
        g[t] = s;
    }
    __syncthreads();
    if (t < C_) {
        float y = g[I_ * C_ + t];   // j = 16 term, x_ext = 1
#pragma unroll
        for (int j = 0; j < I_; ++j)
            y += x[b * I_ + j] * g[j * C_ + t];
        out[Y_OFF + b * C_ + t] = y;
    }
}

extern "C" void kernel_launch(void* const* d_in, const int* in_sizes, int n_in,
                              void* d_out, int out_size, void* d_ws, size_t ws_size,
                              hipStream_t stream) {
    const float* x       = (const float*)d_in[0];
    const float* centers = (const float*)d_in[1];
    const float* widths  = (const float*)d_in[2];
    const float* cons    = (const float*)d_in[3];
    const int*   ridx    = (const int*)d_in[4];
    float* out = (float*)d_out;

    uint32_t* packed = (uint32_t*)d_ws;                     // 16 KB
    float* part = (float*)((char*)d_ws + 16384);            // 8*2048*170*4 = 11.1 MB

    pack_kernel<<<dim3((R_ + 255) / 256), dim3(256), 0, stream>>>(ridx, packed);
    fuzz_kernel<<<dim3(B_), dim3(256), 0, stream>>>(x, centers, widths, packed, out);
    gemm_kernel<<<dim3(B_ / BM, KSPLIT), dim3(256), 0, stream>>>(out + NORM_OFF, cons, part);
    finalize_kernel<<<dim3(B_), dim3(192), 0, stream>>>(part, x, out);
}

// Round 2
// 48.097 us; speedup vs baseline: 3.2402x; 3.2402x over previous
//
#include <hip/hip_runtime.h>
#include <stdint.h>

typedef short short8 __attribute__((ext_vector_type(8)));
typedef float f32x4 __attribute__((ext_vector_type(4)));

#define B_ 2048
#define I_ 16
#define M_ 4
#define R_ 4096
#define C_ 10
#define NX 17           // I+1
#define NW 170          // NX*C
#define NPAD 192        // 12 MFMA n-tiles
#define KSPLIT 16
#define KCH (R_ / KSPLIT)   // 256

// d_out layout: y_hat (B_*C_) | norm_fs (B_*R_) | x_ext (B_*NX)
#define Y_OFF    0
#define NORM_OFF (B_ * C_)
#define XE_OFF   (B_ * C_ + B_ * R_)

// d_ws layout (bytes)
#define PK_OFF    0                                   // packed rule idx, 16 KB
#define WT_OFF    16384                               // Wt bf16 [NPAD][R_], 1.57 MB
#define NFB_OFF   (WT_OFF + NPAD * R_ * 2)            // nf bf16 [B_][R_], 16.8 MB
#define PARTY_OFF (NFB_OFF + B_ * R_ * 2)             // y partials [KSPLIT][B_][C_] f32

#define MFMA16(a, b, c) __builtin_amdgcn_mfma_f32_16x16x32_bf16(a, b, c, 0, 0, 0)

__device__ __forceinline__ uint16_t f2bf(float f) {
    uint32_t u = __builtin_bit_cast(uint32_t, f);
    uint32_t r = u + 0x7fffu + ((u >> 16) & 1u);    // RNE
    return (uint16_t)(r >> 16);
}

// ---------------- pack rule_idx: 16 x 2-bit indices -> one uint32 per rule ----
__global__ void pack_kernel(const int* __restrict__ rule_idx,
                            uint32_t* __restrict__ packed) {
    int r = blockIdx.x * 256 + threadIdx.x;
    if (r < R_) {
        uint32_t p = 0;
#pragma unroll
        for (int i = 0; i < I_; ++i)
            p |= ((uint32_t)rule_idx[i * R_ + r] & 3u) << (2 * i);
        packed[r] = p;
    }
}

// ---------------- transpose consequents -> Wt[n][k] bf16, n padded to 192 ----
__global__ __launch_bounds__(256) void prep_wt(const float* __restrict__ cons,
                                               uint16_t* __restrict__ wt) {
    int n = blockIdx.x;       // 0..NPAD-1
    int t = threadIdx.x;
    for (int kk = 0; kk < R_; kk += 256) {
        int k = kk + t;
        uint16_t v = 0;
        if (n < NW) v = f2bf(cons[(size_t)k * NW + n]);
        wt[(size_t)n * R_ + k] = v;
    }
}

// ---------------- per-batch: mfs pair table, firing, norm_fs(+bf16), x_ext ---
__global__ __launch_bounds__(256) void fuzz_kernel(
        const float* __restrict__ x, const float* __restrict__ centers,
        const float* __restrict__ widths, const uint32_t* __restrict__ packed,
        float* __restrict__ out, uint16_t* __restrict__ nfb) {
    int b = blockIdx.x;
    int t = threadIdx.x;
    __shared__ float xs[I_];
    __shared__ float tab[8 * 16];
    __shared__ float wsum[4];

    if (t < I_) xs[t] = x[b * I_ + t];
    if (t < NX) out[XE_OFF + b * NX + t] = (t < I_) ? x[b * I_ + t] : 1.0f;
    __syncthreads();

    if (t < 128) {
        int q  = t >> 4;
        int hi = (t >> 2) & 3;
        int lo = t & 3;
        int i0 = 2 * q, i1 = 2 * q + 1;
        float d0 = xs[i0] - centers[i0 * M_ + lo];
        float w0 = widths[i0 * M_ + lo];
        float m0 = expf(-(d0 * d0) / (2.0f * w0 * w0) + 1e-9f);
        float d1 = xs[i1] - centers[i1 * M_ + hi];
        float w1 = widths[i1 * M_ + hi];
        float m1 = expf(-(d1 * d1) / (2.0f * w1 * w1) + 1e-9f);
        tab[t] = m0 * m1;
    }
    __syncthreads();

    float fs[16];
    float lsum = 0.f;
#pragma unroll
    for (int k = 0; k < 16; ++k) {
        uint32_t p = packed[t + k * 256];
        float f = tab[        p        & 15];
        f *= tab[ 16 + ((p >>  4) & 15)];
        f *= tab[ 32 + ((p >>  8) & 15)];
        f *= tab[ 48 + ((p >> 12) & 15)];
        f *= tab[ 64 + ((p >> 16) & 15)];
        f *= tab[ 80 + ((p >> 20) & 15)];
        f *= tab[ 96 + ((p >> 24) & 15)];
        f *= tab[112 + ((p >> 28) & 15)];
        fs[k] = f;
        lsum += f;
    }
#pragma unroll
    for (int off = 32; off > 0; off >>= 1) lsum += __shfl_down(lsum, off);
    if ((t & 63) == 0) wsum[t >> 6] = lsum;
    __syncthreads();
    float inv = 1.0f / (wsum[0] + wsum[1] + wsum[2] + wsum[3] + 1e-9f);
#pragma unroll
    for (int k = 0; k < 16; ++k) {
        float v = fs[k] * inv;
        out[NORM_OFF + (size_t)b * R_ + t + k * 256] = v;
        nfb[(size_t)b * R_ + t + k * 256] = f2bf(v);
    }
}

// ---------------- MFMA GEMM + fused x_ext contraction -----------------------
// party[ks][b][c] = sum_{k in slice} nf[b,k] * (sum_j xe[b,j] W[k, j*C+c])
__global__ __launch_bounds__(256) void gemm_kernel(
        const uint16_t* __restrict__ nfb,   // [B_][R_] bf16
        const uint16_t* __restrict__ wt,    // [NPAD][R_] bf16 (= W^T padded)
        const float* __restrict__ xe,       // [B_][NX]
        float* __restrict__ party) {        // [KSPLIT][B_][C_]
    int bt  = blockIdx.x;           // 0..31  (64 batch rows each)
    int ks  = blockIdx.y;           // 0..KSPLIT-1
    int tid = threadIdx.x;
    int wid = tid >> 6;             // wave 0..3 -> n-cols [wid*48, wid*48+48)
    int lane = tid & 63;
    int b0 = bt * 64;
    int k0 = ks * KCH;
    int row = lane & 15;
    int kf  = (lane >> 4) * 8;

    f32x4 acc[4][3];
#pragma unroll
    for (int mt = 0; mt < 4; ++mt)
#pragma unroll
        for (int nt = 0; nt < 3; ++nt) acc[mt][nt] = (f32x4){0.f, 0.f, 0.f, 0.f};

    const uint16_t* Ab = nfb + (size_t)(b0 + row) * R_ + k0 + kf;
    const uint16_t* Bb = wt  + (size_t)(wid * 48 + row) * R_ + k0 + kf;

#pragma unroll 2
    for (int kk = 0; kk < KCH; kk += 32) {
        short8 a0 = *(const short8*)(Ab + kk);
        short8 a1 = *(const short8*)(Ab + (size_t)16 * R_ + kk);
        short8 a2 = *(const short8*)(Ab + (size_t)32 * R_ + kk);
        short8 a3 = *(const short8*)(Ab + (size_t)48 * R_ + kk);
        short8 w0 = *(const short8*)(Bb + kk);
        short8 w1 = *(const short8*)(Bb + (size_t)16 * R_ + kk);
        short8 w2 = *(const short8*)(Bb + (size_t)32 * R_ + kk);
        acc[0][0] = MFMA16(a0, w0, acc[0][0]);
        acc[1][0] = MFMA16(a1, w0, acc[1][0]);
        acc[2][0] = MFMA16(a2, w0, acc[2][0]);
        acc[3][0] = MFMA16(a3, w0, acc[3][0]);
        acc[0][1] = MFMA16(a0, w1, acc[0][1]);
        acc[1][1] = MFMA16(a1, w1, acc[1][1]);
        acc[2][1] = MFMA16(a2, w1, acc[2][1]);
        acc[3][1] = MFMA16(a3, w1, acc[3][1]);
        acc[0][2] = MFMA16(a0, w2, acc[0][2]);
        acc[1][2] = MFMA16(a1, w2, acc[1][2]);
        acc[2][2] = MFMA16(a2, w2, acc[2][2]);
        acc[3][2] = MFMA16(a3, w2, acc[3][2]);
    }

    // C/D layout: col = lane&15, row = (lane>>4)*4 + j   [m89-verified]
    __shared__ float tile[64][NPAD];
#pragma unroll
    for (int mt = 0; mt < 4; ++mt)
#pragma unroll
        for (int nt = 0; nt < 3; ++nt)
#pragma unroll
            for (int j = 0; j < 4; ++j)
                tile[mt * 16 + (lane >> 4) * 4 + j][wid * 48 + nt * 16 + row] =
                    acc[mt][nt][j];
    __syncthreads();

    // contract with x_ext: y[b][c] = sum_j xe[b][j] * tile[b][j*C+c]
    for (int idx = tid; idx < 64 * C_; idx += 256) {
        int bl = idx / C_;
        int c  = idx - bl * C_;
        float y = tile[bl][I_ * C_ + c];      // j = 16, xe = 1
        const float* xrow = xe + (size_t)(b0 + bl) * NX;
#pragma unroll
        for (int j = 0; j < I_; ++j) y += xrow[j] * tile[bl][j * C_ + c];
        party[((size_t)ks * B_ + b0 + bl) * C_ + c] = y;
    }
}

// ---------------- reduce K-split y partials ----------------------------------
__global__ __launch_bounds__(256) void finalize_kernel(
        const float* __restrict__ party, float* __restrict__ out) {
    int idx = blockIdx.x * 256 + threadIdx.x;
    if (idx < B_ * C_) {
        float s = 0.f;
#pragma unroll
        for (int ks = 0; ks < KSPLIT; ++ks) s += party[(size_t)ks * B_ * C_ + idx];
        out[Y_OFF + idx] = s;
    }
}

extern "C" void kernel_launch(void* const* d_in, const int* in_sizes, int n_in,
                              void* d_out, int out_size, void* d_ws, size_t ws_size,
                              hipStream_t stream) {
    const float* x       = (const float*)d_in[0];
    const float* centers = (const float*)d_in[1];
    const float* widths  = (const float*)d_in[2];
    const float* cons    = (const float*)d_in[3];
    const int*   ridx    = (const int*)d_in[4];
    float* out = (float*)d_out;

    uint32_t* packed = (uint32_t*)((char*)d_ws + PK_OFF);
    uint16_t* wt     = (uint16_t*)((char*)d_ws + WT_OFF);
    uint16_t* nfb    = (uint16_t*)((char*)d_ws + NFB_OFF);
    float*    party  = (float*)((char*)d_ws + PARTY_OFF);

    pack_kernel<<<dim3((R_ + 255) / 256), dim3(256), 0, stream>>>(ridx, packed);
    prep_wt<<<dim3(NPAD), dim3(256), 0, stream>>>(cons, wt);
    fuzz_kernel<<<dim3(B_), dim3(256), 0, stream>>>(x, centers, widths, packed, out, nfb);
    gemm_kernel<<<dim3(B_ / 64, KSPLIT), dim3(256), 0, stream>>>(
        nfb, wt, out + XE_OFF, party);
    finalize_kernel<<<dim3((B_ * C_ + 255) / 256), dim3(256), 0, stream>>>(party, out);
}

// Round 3
// 47.122 us; speedup vs baseline: 3.3073x; 1.0207x over previous
//
#include <hip/hip_runtime.h>
#include <stdint.h>

typedef short short8 __attribute__((ext_vector_type(8)));
typedef float f32x4 __attribute__((ext_vector_type(4)));

#define B_ 2048
#define I_ 16
#define M_ 4
#define R_ 4096
#define C_ 10
#define NX 17           // I+1
#define NW 170          // NX*C
#define NPAD 192        // 12 MFMA n-tiles
#define KSPLIT 32
#define KCH (R_ / KSPLIT)   // 128

// d_out layout: y_hat (B_*C_) | norm_fs (B_*R_) | x_ext (B_*NX)
#define Y_OFF    0
#define NORM_OFF (B_ * C_)
#define XE_OFF   (B_ * C_ + B_ * R_)

// d_ws layout (bytes)
#define PK_OFF    0                                   // packed rule idx, 16 KB
#define WT_OFF    16384                               // Wt bf16 [NPAD][R_], 1.57 MB
#define NFB_OFF   (WT_OFF + NPAD * R_ * 2)            // nf bf16 [B_][R_], 16.8 MB
#define PARTY_OFF (NFB_OFF + B_ * R_ * 2)             // y partials [KSPLIT][B_][C_] f32

#define MFMA16(a, b, c) __builtin_amdgcn_mfma_f32_16x16x32_bf16(a, b, c, 0, 0, 0)

__device__ __forceinline__ uint16_t f2bf(float f) {
    uint32_t u = __builtin_bit_cast(uint32_t, f);
    uint32_t r = u + 0x7fffu + ((u >> 16) & 1u);    // RNE
    return (uint16_t)(r >> 16);
}

// ---------------- prep: pack rule_idx (block 64) + transpose W (blocks 0..63)
__global__ __launch_bounds__(256) void prep_kernel(
        const int* __restrict__ rule_idx, const float* __restrict__ cons,
        uint32_t* __restrict__ packed, uint16_t* __restrict__ wt) {
    int t = threadIdx.x;
    if (blockIdx.x == 64) {               // pack: 16 x 2-bit -> uint32 per rule
        for (int r = t; r < R_; r += 256) {
            uint32_t p = 0;
#pragma unroll
            for (int i = 0; i < I_; ++i)
                p |= ((uint32_t)rule_idx[i * R_ + r] & 3u) << (2 * i);
            packed[r] = p;
        }
        return;
    }
    // transpose 64 k-rows of consequents into wt[n][k] bf16 (n padded to NPAD)
    __shared__ float lt[64][NW + 1];
    int k0 = blockIdx.x * 64;
    for (int idx = t; idx < 64 * NW; idx += 256) {
        int k = idx / NW, n = idx - k * NW;
        lt[k][n] = cons[(size_t)(k0 + k) * NW + n];
    }
    __syncthreads();
    for (int idx = t; idx < NPAD * 32; idx += 256) {
        int n = idx >> 5, kp = idx & 31;
        uint32_t v = 0;
        if (n < NW) {
            uint32_t v0 = f2bf(lt[kp * 2][n]);
            uint32_t v1 = f2bf(lt[kp * 2 + 1][n]);
            v = v0 | (v1 << 16);
        }
        *(uint32_t*)(wt + (size_t)n * R_ + k0 + kp * 2) = v;
    }
}

// ---------------- per-batch: log-space quad tables, firing, norm_fs, x_ext ---
__global__ __launch_bounds__(256) void fuzz_kernel(
        const float* __restrict__ x, const float* __restrict__ centers,
        const float* __restrict__ widths, const uint32_t* __restrict__ packed,
        float* __restrict__ out, uint16_t* __restrict__ nfb) {
    int b = blockIdx.x;
    int t = threadIdx.x;
    __shared__ float xs[I_];
    __shared__ float zl[64];        // zl[i*4+m] = -(x_i-c_im)^2/(2 w_im^2) + 1e-9
    __shared__ float tab4[4 * 256]; // quad q: sum of 4 zl terms, 8-bit combo idx
    __shared__ float wsum[4];

    if (t < I_) xs[t] = x[b * I_ + t];
    if (t < NX) out[XE_OFF + b * NX + t] = (t < I_) ? x[b * I_ + t] : 1.0f;
    __syncthreads();

    if (t < 64) {
        int i = t >> 2, m = t & 3;
        float d = xs[i] - centers[i * M_ + m];
        float w = widths[i * M_ + m];
        zl[t] = -(d * d) / (2.0f * w * w) + 1e-9f;
    }
    __syncthreads();

#pragma unroll
    for (int u = 0; u < 4; ++u) {
        int idx = t + u * 256;
        int q = idx >> 8, xq = idx & 255;
        tab4[idx] = zl[q * 16 +      (xq & 3)]
                  + zl[q * 16 +  4 + ((xq >> 2) & 3)]
                  + zl[q * 16 +  8 + ((xq >> 4) & 3)]
                  + zl[q * 16 + 12 + ((xq >> 6) & 3)];
    }
    __syncthreads();

    float fs[16];
    float lsum = 0.f;
#pragma unroll
    for (int k = 0; k < 16; ++k) {
        uint32_t p = packed[t + k * 256];
        float s = tab4[        p         & 255]
                + tab4[256 + ((p >>  8) & 255)]
                + tab4[512 + ((p >> 16) & 255)]
                + tab4[768 + ((p >> 24) & 255)];
        float f = __expf(s);
        fs[k] = f;
        lsum += f;
    }
#pragma unroll
    for (int off = 32; off > 0; off >>= 1) lsum += __shfl_down(lsum, off);
    if ((t & 63) == 0) wsum[t >> 6] = lsum;
    __syncthreads();
    float inv = 1.0f / (wsum[0] + wsum[1] + wsum[2] + wsum[3] + 1e-9f);
#pragma unroll
    for (int k = 0; k < 16; ++k) {
        float v = fs[k] * inv;
        out[NORM_OFF + (size_t)b * R_ + t + k * 256] = v;
        nfb[(size_t)b * R_ + t + k * 256] = f2bf(v);
    }
}

// ---------------- MFMA GEMM + fused x_ext contraction -----------------------
__global__ __launch_bounds__(256, 3) void gemm_kernel(
        const uint16_t* __restrict__ nfb,   // [B_][R_] bf16
        const uint16_t* __restrict__ wt,    // [NPAD][R_] bf16 (= W^T padded)
        const float* __restrict__ xe,       // [B_][NX]
        float* __restrict__ party) {        // [KSPLIT][B_][C_]
    int bt  = blockIdx.x;           // 0..31
    int ks  = blockIdx.y;           // 0..KSPLIT-1
    int tid = threadIdx.x;
    int wid = tid >> 6;
    int lane = tid & 63;
    int b0 = bt * 64;
    int k0 = ks * KCH;
    int row = lane & 15;
    int kf  = (lane >> 4) * 8;

    f32x4 acc[4][3];
#pragma unroll
    for (int mt = 0; mt < 4; ++mt)
#pragma unroll
        for (int nt = 0; nt < 3; ++nt) acc[mt][nt] = (f32x4){0.f, 0.f, 0.f, 0.f};

    const uint16_t* Ab = nfb + (size_t)(b0 + row) * R_ + k0 + kf;
    const uint16_t* Bb = wt  + (size_t)(wid * 48 + row) * R_ + k0 + kf;

    short8 a[2][4], w[2][3];
#define LOADS(buf, kk)                                                   \
    do {                                                                 \
        a[buf][0] = *(const short8*)(Ab + (kk));                         \
        a[buf][1] = *(const short8*)(Ab + (size_t)16 * R_ + (kk));       \
        a[buf][2] = *(const short8*)(Ab + (size_t)32 * R_ + (kk));       \
        a[buf][3] = *(const short8*)(Ab + (size_t)48 * R_ + (kk));       \
        w[buf][0] = *(const short8*)(Bb + (kk));                         \
        w[buf][1] = *(const short8*)(Bb + (size_t)16 * R_ + (kk));       \
        w[buf][2] = *(const short8*)(Bb + (size_t)32 * R_ + (kk));       \
    } while (0)

    LOADS(0, 0);
#pragma unroll
    for (int it = 0; it < KCH / 32; ++it) {
        int cur = it & 1;
        if (it + 1 < KCH / 32) LOADS(cur ^ 1, (it + 1) * 32);
#pragma unroll
        for (int nt = 0; nt < 3; ++nt)
#pragma unroll
            for (int mt = 0; mt < 4; ++mt)
                acc[mt][nt] = MFMA16(a[cur][mt], w[cur][nt], acc[mt][nt]);
    }
#undef LOADS

    // C/D layout: col = lane&15, row = (lane>>4)*4 + j
    __shared__ float tile[64][NPAD];
#pragma unroll
    for (int mt = 0; mt < 4; ++mt)
#pragma unroll
        for (int nt = 0; nt < 3; ++nt)
#pragma unroll
            for (int j = 0; j < 4; ++j)
                tile[mt * 16 + (lane >> 4) * 4 + j][wid * 48 + nt * 16 + row] =
                    acc[mt][nt][j];
    __syncthreads();

    for (int idx = tid; idx < 64 * C_; idx += 256) {
        int bl = idx / C_;
        int c  = idx - bl * C_;
        float y = tile[bl][I_ * C_ + c];      // j = 16, xe = 1
        const float* xrow = xe + (size_t)(b0 + bl) * NX;
#pragma unroll
        for (int j = 0; j < I_; ++j) y += xrow[j] * tile[bl][j * C_ + c];
        party[((size_t)ks * B_ + b0 + bl) * C_ + c] = y;
    }
}

// ---------------- reduce K-split y partials ----------------------------------
__global__ __launch_bounds__(256) void finalize_kernel(
        const float* __restrict__ party, float* __restrict__ out) {
    int idx = blockIdx.x * 256 + threadIdx.x;
    if (idx < B_ * C_) {
        float s = 0.f;
#pragma unroll
        for (int ks = 0; ks < KSPLIT; ++ks) s += party[(size_t)ks * B_ * C_ + idx];
        out[Y_OFF + idx] = s;
    }
}

extern "C" void kernel_launch(void* const* d_in, const int* in_sizes, int n_in,
                              void* d_out, int out_size, void* d_ws, size_t ws_size,
                              hipStream_t stream) {
    const float* x       = (const float*)d_in[0];
    const float* centers = (const float*)d_in[1];
    const float* widths  = (const float*)d_in[2];
    const float* cons    = (const float*)d_in[3];
    const int*   ridx    = (const int*)d_in[4];
    float* out = (float*)d_out;

    uint32_t* packed = (uint32_t*)((char*)d_ws + PK_OFF);
    uint16_t* wt     = (uint16_t*)((char*)d_ws + WT_OFF);
    uint16_t* nfb    = (uint16_t*)((char*)d_ws + NFB_OFF);
    float*    party  = (float*)((char*)d_ws + PARTY_OFF);

    prep_kernel<<<dim3(65), dim3(256), 0, stream>>>(ridx, cons, packed, wt);
    fuzz_kernel<<<dim3(B_), dim3(256), 0, stream>>>(x, centers, widths, packed, out, nfb);
    gemm_kernel<<<dim3(B_ / 64, KSPLIT), dim3(256), 0, stream>>>(
        nfb, wt, out + XE_OFF, party);
    finalize_kernel<<<dim3((B_ * C_ + 255) / 256), dim3(256), 0, stream>>>(party, out);
}